// Round 1
// baseline (832.595 us; speedup 1.0000x reference)
//
#include <hip/hip_runtime.h>

typedef __bf16 bf16;
typedef __bf16 bf16x8 __attribute__((ext_vector_type(8)));
typedef float f32x4 __attribute__((ext_vector_type(4)));

#define CCH 128  // channels (all layers 128 -> 128)

// ---------------- prep: weights (O,I,K) fp32 -> wT[k][o][i] bf16 ----------------
__global__ void k_prep_w(const float* __restrict__ w, bf16* __restrict__ wT,
                         int Kw, int total) {
    int idx = blockIdx.x * 256 + threadIdx.x;
    if (idx >= total) return;
    int i = idx & 127;
    int o = (idx >> 7) & 127;
    int k = idx >> 14;
    wT[idx] = (bf16)w[(o * 128 + i) * Kw + k];
}

// ---------------- prep: centers fp32 -> bf16, plus ||c||^2 ----------------
__global__ void k_prep_c(const float* __restrict__ c, bf16* __restrict__ cb,
                         float* __restrict__ cc) {
    int k = blockIdx.x;
    int tid = threadIdx.x;
    const float* row = c + k * 7552;
    bf16* orow = cb + k * 7552;
    float s = 0.f;
    for (int d = tid; d < 7552; d += 256) {
        bf16 b = (bf16)row[d];
        orow[d] = b;
        float v = (float)b;
        s += v * v;
    }
    __shared__ float red[256];
    red[tid] = s;
    __syncthreads();
    for (int st = 128; st > 0; st >>= 1) {
        if (tid < st) red[tid] += red[tid + st];
        __syncthreads();
    }
    if (tid == 0) cc[k] = red[0];
}

// ---------------- conv layer: implicit GEMM, bf16 MFMA ----------------
// out[n][o][l] = act( sum_{i,k} w[o][i][k] * in[n][i][2*l+k] + bias[o] )
// GEMM: m=o (128), n=l (LT tile), K = i within 32-chunk at fixed tap k.
// A-frag: wT[k][o][i0+quad*8..+7]  -> contiguous 16B global load (L1/L2-hot).
// B-frag: LDS tile, p-major rows of 64 bf16 (128B), slot-swizzled so the
//         16B read (8 consecutive i) is 2-way bank aliased (free).
template <int KW, int L_IN, int L_OUT, int LT, bool ACT, bool IN_F32>
__global__ __launch_bounds__(256, 3) void k_conv(
    const void* __restrict__ in_, const bf16* __restrict__ wT,
    const float* __restrict__ bias, bf16* __restrict__ out) {
    constexpr int P = (LT - 1) * 2 + KW;  // input positions needed by this tile
    constexpr int WLS = LT / 2;           // l-span per wave
    constexpr int NLT = WLS / 16;         // 16-wide l-tiles per wave
    __shared__ __align__(16) bf16 tile[P * 64];

    const int n = blockIdx.y;
    const int l0 = blockIdx.x * LT;
    const int p0 = l0 * 2;
    const int tid = threadIdx.x;
    const int wid = tid >> 6;
    const int lane = tid & 63;
    const int quad = lane >> 4;
    const int l15 = lane & 15;
    const int wave_o = (wid >> 1) * 64;   // 2x2 wave grid: 64o x WLS l per wave
    const int wave_l = (wid & 1) * WLS;

    const float* __restrict__ inF = (const float*)in_;
    const bf16* __restrict__ inB = (const bf16*)in_;

    f32x4 acc[4][NLT];
#pragma unroll
    for (int a = 0; a < 4; ++a)
#pragma unroll
        for (int b = 0; b < NLT; ++b) acc[a][b] = (f32x4){0.f, 0.f, 0.f, 0.f};

#pragma unroll 1
    for (int phase = 0; phase < 2; ++phase) {
        __syncthreads();  // protect tile against overwrite (phase 1)
        const int cbase = phase * 64;
        // stage channels [cbase, cbase+64) x positions [p0, p0+P) -> swizzled LDS
        for (int idx = tid; idx < 64 * P; idx += 256) {
            int i = idx / P;          // local channel 0..63
            int p = idx - i * P;      // position 0..P-1 (consecutive tid -> coalesced)
            int gp = p0 + p;
            float v = 0.f;
            if (gp < L_IN) {
                int off = (n * CCH + cbase + i) * L_IN + gp;
                v = IN_F32 ? inF[off] : (float)inB[off];
            }
            int slot = (i >> 3) ^ ((p >> 1) & 7);
            tile[p * 64 + slot * 8 + (i & 7)] = (bf16)v;
        }
        __syncthreads();

#pragma unroll 2
        for (int k = 0; k < KW; ++k) {
#pragma unroll
            for (int ic = 0; ic < 2; ++ic) {
                const int i0g = cbase + ic * 32;  // global channel chunk base
                bf16x8 afr[4];
#pragma unroll
                for (int ot = 0; ot < 4; ++ot) {
                    int o = wave_o + ot * 16 + l15;
                    afr[ot] = *(const bf16x8*)(wT + (k * CCH + o) * CCH + i0g + quad * 8);
                }
                bf16x8 bfr[NLT];
#pragma unroll
                for (int lt = 0; lt < NLT; ++lt) {
                    int p = (wave_l + lt * 16 + l15) * 2 + k;  // tile-local position
                    int ig = ic * 32 + quad * 8;               // tile-local channel
                    int slot = (ig >> 3) ^ ((p >> 1) & 7);
                    bfr[lt] = *(const bf16x8*)(tile + p * 64 + slot * 8);
                }
#pragma unroll
                for (int ot = 0; ot < 4; ++ot)
#pragma unroll
                    for (int lt = 0; lt < NLT; ++lt)
                        acc[ot][lt] = __builtin_amdgcn_mfma_f32_16x16x32_bf16(
                            afr[ot], bfr[lt], acc[ot][lt], 0, 0, 0);
            }
        }
    }

    // epilogue: C/D layout col=lane&15 (l), row=quad*4+r (o)
#pragma unroll
    for (int ot = 0; ot < 4; ++ot) {
        const int obase = wave_o + ot * 16 + quad * 4;
#pragma unroll
        for (int lt = 0; lt < NLT; ++lt) {
            const int l = l0 + wave_l + lt * 16 + l15;
            if (l < L_OUT) {
#pragma unroll
                for (int r = 0; r < 4; ++r) {
                    float v = acc[ot][lt][r] + bias[obase + r];
                    if (ACT) v = (v > 0.f) ? v : 0.1f * v;
                    out[(n * CCH + obase + r) * L_OUT + l] = (bf16)v;
                }
            }
        }
    }
}

// ---------------- distances + Student-t assignment ----------------
// one block per batch row n; q_k = (1/(1+d2_k)) / sum_j (1/(1+d2_j))
__global__ void k_dist(const bf16* __restrict__ z, const bf16* __restrict__ cb,
                       const float* __restrict__ cc, float* __restrict__ out) {
    __shared__ float zsh[7552];
    __shared__ float red[256];
    __shared__ float qsh[64];
    const int n = blockIdx.x;
    const int tid = threadIdx.x;
    const bf16* zr = z + n * 7552;
    float zz = 0.f;
    for (int d = tid; d < 7552; d += 256) {
        float v = (float)zr[d];
        zsh[d] = v;
        zz += v * v;
    }
    red[tid] = zz;
    __syncthreads();
    for (int st = 128; st > 0; st >>= 1) {
        if (tid < st) red[tid] += red[tid + st];
        __syncthreads();
    }
    const float zz_val = red[0];
    __syncthreads();  // all threads have read red[0] before red is reused

    const int k = tid >> 2;    // center 0..63
    const int part = tid & 3;  // quarter of D
    const bf16* cr = cb + k * 7552 + part * 1888;
    const float* zp = zsh + part * 1888;
    float s = 0.f;
    for (int d = 0; d < 1888; d += 8) {
        bf16x8 cv = *(const bf16x8*)(cr + d);
#pragma unroll
        for (int j = 0; j < 8; ++j) s += zp[d + j] * (float)cv[j];
    }
    red[tid] = s;
    __syncthreads();
    if (tid < 64) {
        float dot = red[tid * 4] + red[tid * 4 + 1] + red[tid * 4 + 2] + red[tid * 4 + 3];
        float d2 = zz_val + cc[tid] - 2.f * dot;
        qsh[tid] = 1.f / (1.f + d2);  // ALPHA=1, exponent (ALPHA+1)/2 == 1
    }
    __syncthreads();
    if (tid < 64) {
        float q = qsh[tid];
        float tot = q;
        for (int o = 32; o > 0; o >>= 1) tot += __shfl_down(tot, o);
        tot = __shfl(tot, 0);
        out[n * 64 + tid] = q / tot;
    }
}

// ---------------- launcher ----------------
extern "C" void kernel_launch(void* const* d_in, const int* in_sizes, int n_in,
                              void* d_out, int out_size, void* d_ws, size_t ws_size,
                              hipStream_t stream) {
    (void)in_sizes; (void)n_in; (void)out_size; (void)ws_size;
    const float* x   = (const float*)d_in[0];
    const float* w1  = (const float*)d_in[1];
    const float* b1  = (const float*)d_in[2];
    const float* w2  = (const float*)d_in[3];
    const float* b2  = (const float*)d_in[4];
    const float* w3  = (const float*)d_in[5];
    const float* b3  = (const float*)d_in[6];
    const float* w4  = (const float*)d_in[7];
    const float* b4  = (const float*)d_in[8];
    const float* cen = (const float*)d_in[9];
    float* out = (float*)d_out;

    char* ws = (char*)d_ws;
    size_t off = 0;
    auto alloc = [&](size_t bytes) -> void* {
        void* p = ws + off;
        off += (bytes + 255) & ~(size_t)255;
        return p;
    };
    bf16* wT1 = (bf16*)alloc((size_t)15 * 16384 * sizeof(bf16));
    bf16* wT2 = (bf16*)alloc((size_t)12 * 16384 * sizeof(bf16));
    bf16* wT3 = (bf16*)alloc((size_t)7 * 16384 * sizeof(bf16));
    bf16* wT4 = (bf16*)alloc((size_t)4 * 16384 * sizeof(bf16));
    bf16* cb  = (bf16*)alloc((size_t)64 * 7552 * sizeof(bf16));
    float* cc = (float*)alloc(64 * sizeof(float));
    bf16* h1  = (bf16*)alloc((size_t)256 * 128 * 505 * sizeof(bf16));
    bf16* h2  = (bf16*)alloc((size_t)256 * 128 * 247 * sizeof(bf16));
    bf16* h3  = h1;  // reuse: h1 dead after conv2
    bf16* h4  = h2;  // reuse: h2 dead after conv3

    k_prep_w<<<(15 * 16384 + 255) / 256, 256, 0, stream>>>(w1, wT1, 15, 15 * 16384);
    k_prep_w<<<(12 * 16384 + 255) / 256, 256, 0, stream>>>(w2, wT2, 12, 12 * 16384);
    k_prep_w<<<(7 * 16384 + 255) / 256, 256, 0, stream>>>(w3, wT3, 7, 7 * 16384);
    k_prep_w<<<(4 * 16384 + 255) / 256, 256, 0, stream>>>(w4, wT4, 4, 4 * 16384);
    k_prep_c<<<64, 256, 0, stream>>>(cen, cb, cc);

    // conv1: 1024 -> 505 (K=15), LeakyReLU, fp32 input
    k_conv<15, 1024, 505, 128, true, true><<<dim3(4, 256), 256, 0, stream>>>(x, wT1, b1, h1);
    // conv2: 505 -> 247 (K=12), LeakyReLU
    k_conv<12, 505, 247, 128, true, false><<<dim3(2, 256), 256, 0, stream>>>(h1, wT2, b2, h2);
    // conv3: 247 -> 121 (K=7), LeakyReLU
    k_conv<7, 247, 121, 128, true, false><<<dim3(1, 256), 256, 0, stream>>>(h2, wT3, b3, h3);
    // conv4: 121 -> 59 (K=4), no activation
    k_conv<4, 121, 59, 64, false, false><<<dim3(1, 256), 256, 0, stream>>>(h3, wT4, b4, h4);

    k_dist<<<256, 256, 0, stream>>>(h4, cb, cc, out);
}

// Round 2
// 617.145 us; speedup vs baseline: 1.3491x; 1.3491x over previous
//
#include <hip/hip_runtime.h>

typedef __bf16 bf16;
typedef __bf16 bf16x8 __attribute__((ext_vector_type(8)));
typedef float f32x4 __attribute__((ext_vector_type(4)));

#define CCH 128  // channels (all layers 128 -> 128)

// ---------------- prep: weights (O,I,K) fp32 -> wT[k][o][i] bf16 ----------------
__global__ void k_prep_w(const float* __restrict__ w, bf16* __restrict__ wT,
                         int Kw, int total) {
    int idx = blockIdx.x * 256 + threadIdx.x;
    if (idx >= total) return;
    int i = idx & 127;
    int o = (idx >> 7) & 127;
    int k = idx >> 14;
    wT[idx] = (bf16)w[(o * 128 + i) * Kw + k];
}

// ---------------- prep: centers fp32 -> bf16, plus ||c||^2 ----------------
__global__ void k_prep_c(const float* __restrict__ c, bf16* __restrict__ cb,
                         float* __restrict__ cc) {
    int k = blockIdx.x;
    int tid = threadIdx.x;
    const float* row = c + k * 7552;
    bf16* orow = cb + k * 7552;
    float s = 0.f;
    for (int d = tid; d < 7552; d += 256) {
        bf16 b = (bf16)row[d];
        orow[d] = b;
        float v = (float)b;
        s += v * v;
    }
    __shared__ float red[256];
    red[tid] = s;
    __syncthreads();
    for (int st = 128; st > 0; st >>= 1) {
        if (tid < st) red[tid] += red[tid + st];
        __syncthreads();
    }
    if (tid == 0) cc[k] = red[0];
}

// ---------------- conv layer: implicit GEMM, bf16 MFMA ----------------
// out[n][o][l] = act( sum_{i,k} w[o][i][k] * in[n][i][2*l+k] + bias[o] )
// m=o (128), n=l (LT tile), K = 32-channel chunk at fixed tap k.
// A: wT[k][o][i] 16B global loads, register double-buffered (prefetch j+1).
// B: LDS tile, rows of 64 ch per position, 16B slots swizzled
//    slot=(i>>3)^((p>>2)&7): B-reads optimal (8 acc/bank), staging writes 8-way.
// Epilogue: LDS transpose -> 16B stores to 128-elem-aligned padded rows.
template <int KW, int LIN_S, int LIN_V, int LOUT_S, int LOUT_V, int LT, bool ACT, bool IN_F32>
__global__ __launch_bounds__(256, 3) void k_conv(
    const void* __restrict__ in_, const bf16* __restrict__ wT,
    const float* __restrict__ bias, bf16* __restrict__ out) {
    constexpr int P = (LT - 1) * 2 + KW;   // input positions needed by this tile
    constexpr int PP = (P + 7) & ~7;       // padded to vec width
    constexpr int VW = IN_F32 ? 4 : 8;     // elems per 16B staging load
    constexpr int NV = PP / VW;            // vec chunks per channel row
    constexpr int TOT = 64 * NV;           // staging units per phase
    constexpr int NIT = (TOT + 255) / 256;
    constexpr bool TGUARD = (TOT & 255) != 0;
    constexpr int WLS = LT / 2;            // l-span per wave
    constexpr int NLT = WLS / 16;          // 16-wide l-tiles per wave
    constexpr int SE = LT + 8;             // epilogue LDS row stride
    constexpr int SM = (PP * 64 > 128 * SE) ? PP * 64 : 128 * SE;
    __shared__ __align__(16) bf16 smem[SM];

    const int n = blockIdx.y;
    const int l0 = blockIdx.x * LT;
    const int p0 = l0 * 2;
    const int tid = threadIdx.x;
    const int wid = tid >> 6;
    const int lane = tid & 63;
    const int quad = lane >> 4;
    const int l15 = lane & 15;
    const int wave_o = (wid >> 1) * 64;   // 2x2 wave grid: 64o x WLS l per wave
    const int wave_l = (wid & 1) * WLS;

    const float* __restrict__ inF = (const float*)in_;
    const bf16* __restrict__ inB = (const bf16*)in_;

    f32x4 acc[4][NLT];
#pragma unroll
    for (int a = 0; a < 4; ++a)
#pragma unroll
        for (int b = 0; b < NLT; ++b) acc[a][b] = (f32x4){0.f, 0.f, 0.f, 0.f};

    bf16x8 afr[2][4];

#pragma unroll 1
    for (int phase = 0; phase < 2; ++phase) {
        const int cbase = phase * 64;
        __syncthreads();  // protect smem against overwrite (phase 1)

        // prefetch A for j=0 of this phase (global; overlaps staging)
        {
            const bf16* wp = wT + (size_t)(wave_o + l15) * CCH + cbase + quad * 8;
#pragma unroll
            for (int ot = 0; ot < 4; ++ot) afr[0][ot] = *(const bf16x8*)(wp + ot * 16 * CCH);
        }

        // stage channels [cbase, cbase+64) x positions [p0, p0+PP) -> swizzled LDS
#pragma unroll
        for (int it = 0; it < NIT; ++it) {
            int idx = tid + it * 256;
            if (TGUARD && idx >= TOT) continue;
            int i = idx / NV;               // local channel 0..63
            int v = idx - i * NV;           // vec chunk (consecutive tid -> coalesced)
            int gp0 = p0 + v * VW;
            float vals[VW];
            const char* rowb = IN_F32
                ? (const char*)(inF + (size_t)(n * CCH + cbase + i) * LIN_S)
                : (const char*)(inB + (size_t)(n * CCH + cbase + i) * LIN_S);
            if (gp0 + VW <= LIN_V) {
                if (IN_F32) {
                    f32x4 t = *(const f32x4*)((const float*)rowb + gp0);
#pragma unroll
                    for (int e = 0; e < VW; ++e) vals[e] = t[e & 3];
                } else {
                    bf16x8 t = *(const bf16x8*)((const bf16*)rowb + gp0);
#pragma unroll
                    for (int e = 0; e < VW; ++e) vals[e] = (float)t[e & 7];
                }
            } else {
#pragma unroll
                for (int e = 0; e < VW; ++e) {
                    int gp = gp0 + e;
                    vals[e] = 0.f;
                    if (gp < LIN_V)
                        vals[e] = IN_F32 ? ((const float*)rowb)[gp] : (float)((const bf16*)rowb)[gp];
                }
            }
#pragma unroll
            for (int e = 0; e < VW; ++e) {
                int p = v * VW + e;
                int slot = (i >> 3) ^ ((p >> 2) & 7);
                smem[p * 64 + slot * 8 + (i & 7)] = (bf16)vals[e];
            }
        }
        __syncthreads();

        // K-loop: j = (k, ic) flattened; A double-buffered one iter ahead
#pragma unroll 2
        for (int j = 0; j < 2 * KW; ++j) {
            if (j + 1 < 2 * KW) {
                int k1 = (j + 1) >> 1;
                int i01 = cbase + ((j + 1) & 1) * 32 + quad * 8;
                const bf16* wp = wT + (size_t)(k1 * CCH + wave_o + l15) * CCH + i01;
#pragma unroll
                for (int ot = 0; ot < 4; ++ot)
                    afr[(j + 1) & 1][ot] = *(const bf16x8*)(wp + ot * 16 * CCH);
            }
            const int k = j >> 1;
            const int icq = (j & 1) * 4 + quad;  // (ic*32 + quad*8) >> 3
            bf16x8 bfr[NLT];
#pragma unroll
            for (int lt = 0; lt < NLT; ++lt) {
                int p = (wave_l + lt * 16 + l15) * 2 + k;
                int slot = icq ^ ((p >> 2) & 7);
                bfr[lt] = *(const bf16x8*)(smem + p * 64 + slot * 8);
            }
#pragma unroll
            for (int ot = 0; ot < 4; ++ot)
#pragma unroll
                for (int lt = 0; lt < NLT; ++lt)
                    acc[ot][lt] = __builtin_amdgcn_mfma_f32_16x16x32_bf16(
                        afr[j & 1][ot], bfr[lt], acc[ot][lt], 0, 0, 0);
        }
    }

    // ---- epilogue: bias+act, LDS transpose, wide contiguous stores ----
    __syncthreads();  // all B-reads of smem done
#pragma unroll
    for (int ot = 0; ot < 4; ++ot) {
        const int o0 = wave_o + ot * 16 + quad * 4;
#pragma unroll
        for (int lt = 0; lt < NLT; ++lt) {
            const int l = wave_l + lt * 16 + l15;
#pragma unroll
            for (int r = 0; r < 4; ++r) {
                float v = acc[ot][lt][r] + bias[o0 + r];
                if (ACT) v = (v > 0.f) ? v : 0.1f * v;
                smem[(o0 + r) * SE + l] = (bf16)v;
            }
        }
    }
    __syncthreads();
    constexpr int GPR = LT / 8;  // 16B groups per o-row (pow2)
#pragma unroll
    for (int it = 0; it < 128 * GPR / 256; ++it) {
        int unit = tid + it * 256;
        int o = unit / GPR;
        int g = unit & (GPR - 1);
        bf16x8 vv = *(const bf16x8*)(smem + o * SE + g * 8);
        *(bf16x8*)(out + (size_t)(n * CCH + o) * LOUT_S + l0 + g * 8) = vv;
    }
}

// ---------------- distances + Student-t assignment ----------------
// z rows padded: stride 64, valid 59; dense d = o*59 + l matches centers.
__global__ void k_dist(const bf16* __restrict__ z, const bf16* __restrict__ cb,
                       const float* __restrict__ cc, float* __restrict__ out) {
    __shared__ float zsh[7552];
    __shared__ float red[256];
    __shared__ float qsh[64];
    const int n = blockIdx.x;
    const int tid = threadIdx.x;
    const bf16* zr = z + (size_t)n * CCH * 64;
    float zz = 0.f;
    for (int dd = tid; dd < 7552; dd += 256) {
        int o = dd / 59;
        int l = dd - o * 59;
        float v = (float)zr[o * 64 + l];
        zsh[dd] = v;
        zz += v * v;
    }
    red[tid] = zz;
    __syncthreads();
    for (int st = 128; st > 0; st >>= 1) {
        if (tid < st) red[tid] += red[tid + st];
        __syncthreads();
    }
    const float zz_val = red[0];
    __syncthreads();  // all threads have read red[0] before red is reused

    const int k = tid >> 2;    // center 0..63
    const int part = tid & 3;  // quarter of D
    const bf16* cr = cb + k * 7552 + part * 1888;
    const float* zp = zsh + part * 1888;
    float s = 0.f;
    for (int d = 0; d < 1888; d += 8) {
        bf16x8 cv = *(const bf16x8*)(cr + d);
        f32x4 z0 = *(const f32x4*)(zp + d);
        f32x4 z1 = *(const f32x4*)(zp + d + 4);
#pragma unroll
        for (int j = 0; j < 4; ++j) s += z0[j] * (float)cv[j];
#pragma unroll
        for (int j = 0; j < 4; ++j) s += z1[j] * (float)cv[4 + j];
    }
    red[tid] = s;
    __syncthreads();
    if (tid < 64) {
        float dot = red[tid * 4] + red[tid * 4 + 1] + red[tid * 4 + 2] + red[tid * 4 + 3];
        float d2 = zz_val + cc[tid] - 2.f * dot;
        qsh[tid] = 1.f / (1.f + d2);  // ALPHA=1, exponent (ALPHA+1)/2 == 1
    }
    __syncthreads();
    if (tid < 64) {
        float q = qsh[tid];
        float tot = q;
        for (int o = 32; o > 0; o >>= 1) tot += __shfl_down(tot, o);
        tot = __shfl(tot, 0);
        out[n * 64 + tid] = q / tot;
    }
}

// ---------------- launcher ----------------
extern "C" void kernel_launch(void* const* d_in, const int* in_sizes, int n_in,
                              void* d_out, int out_size, void* d_ws, size_t ws_size,
                              hipStream_t stream) {
    (void)in_sizes; (void)n_in; (void)out_size; (void)ws_size;
    const float* x   = (const float*)d_in[0];
    const float* w1  = (const float*)d_in[1];
    const float* b1  = (const float*)d_in[2];
    const float* w2  = (const float*)d_in[3];
    const float* b2  = (const float*)d_in[4];
    const float* w3  = (const float*)d_in[5];
    const float* b3  = (const float*)d_in[6];
    const float* w4  = (const float*)d_in[7];
    const float* b4  = (const float*)d_in[8];
    const float* cen = (const float*)d_in[9];
    float* out = (float*)d_out;

    char* ws = (char*)d_ws;
    size_t off = 0;
    auto alloc = [&](size_t bytes) -> void* {
        void* p = ws + off;
        off += (bytes + 255) & ~(size_t)255;
        return p;
    };
    bf16* wT1 = (bf16*)alloc((size_t)15 * 16384 * sizeof(bf16));
    bf16* wT2 = (bf16*)alloc((size_t)12 * 16384 * sizeof(bf16));
    bf16* wT3 = (bf16*)alloc((size_t)7 * 16384 * sizeof(bf16));
    bf16* wT4 = (bf16*)alloc((size_t)4 * 16384 * sizeof(bf16));
    bf16* cb  = (bf16*)alloc((size_t)64 * 7552 * sizeof(bf16));
    float* cc = (float*)alloc(64 * sizeof(float));
    // padded intermediates: strides 512/256/128/64 (16B-aligned rows)
    bf16* h1  = (bf16*)alloc((size_t)256 * 128 * 512 * sizeof(bf16));
    bf16* h2  = (bf16*)alloc((size_t)256 * 128 * 256 * sizeof(bf16));
    bf16* h3  = h1;  // reuse: h1 dead after conv2 (needs 128-stride)
    bf16* h4  = h2;  // reuse: h2 dead after conv3 (needs 64-stride)

    k_prep_w<<<(15 * 16384 + 255) / 256, 256, 0, stream>>>(w1, wT1, 15, 15 * 16384);
    k_prep_w<<<(12 * 16384 + 255) / 256, 256, 0, stream>>>(w2, wT2, 12, 12 * 16384);
    k_prep_w<<<(7 * 16384 + 255) / 256, 256, 0, stream>>>(w3, wT3, 7, 7 * 16384);
    k_prep_w<<<(4 * 16384 + 255) / 256, 256, 0, stream>>>(w4, wT4, 4, 4 * 16384);
    k_prep_c<<<64, 256, 0, stream>>>(cen, cb, cc);

    // conv1: 1024 -> 505(512) K=15, LeakyReLU, fp32 input
    k_conv<15, 1024, 1024, 512, 505, 128, true, true>
        <<<dim3(4, 256), 256, 0, stream>>>(x, wT1, b1, h1);
    // conv2: 505(512) -> 247(256) K=12, LeakyReLU
    k_conv<12, 512, 505, 256, 247, 128, true, false>
        <<<dim3(2, 256), 256, 0, stream>>>(h1, wT2, b2, h2);
    // conv3: 247(256) -> 121(128) K=7, LeakyReLU
    k_conv<7, 256, 247, 128, 121, 64, true, false>
        <<<dim3(2, 256), 256, 0, stream>>>(h2, wT3, b3, h3);
    // conv4: 121(128) -> 59(64) K=4, no activation
    k_conv<4, 128, 121, 64, 59, 32, false, false>
        <<<dim3(2, 256), 256, 0, stream>>>(h3, wT4, b4, h4);

    k_dist<<<256, 256, 0, stream>>>(h4, cb, cc, out);
}

// Round 3
// 526.087 us; speedup vs baseline: 1.5826x; 1.1731x over previous
//
#include <hip/hip_runtime.h>

typedef __bf16 bf16;
typedef __bf16 bf16x8 __attribute__((ext_vector_type(8)));
typedef float f32x4 __attribute__((ext_vector_type(4)));

#define CCH 128  // channels (all layers 128 -> 128)

// ---------------- prep: all 4 weight tensors (O,I,K) fp32 -> wT[k][o][i] bf16 ----------------
__global__ void k_prep_wall(const float* __restrict__ w1, const float* __restrict__ w2,
                            const float* __restrict__ w3, const float* __restrict__ w4,
                            bf16* __restrict__ o1, bf16* __restrict__ o2,
                            bf16* __restrict__ o3, bf16* __restrict__ o4) {
    int idx = blockIdx.x * 256 + threadIdx.x;
    const float* src; bf16* dst; int Kw; int r = idx;
    if (r < 15 * 16384) { src = w1; dst = o1; Kw = 15; }
    else if ((r -= 15 * 16384) < 12 * 16384) { src = w2; dst = o2; Kw = 12; }
    else if ((r -= 12 * 16384) < 7 * 16384) { src = w3; dst = o3; Kw = 7; }
    else if ((r -= 7 * 16384) < 4 * 16384) { src = w4; dst = o4; Kw = 4; }
    else return;
    int i = r & 127;
    int o = (r >> 7) & 127;
    int k = r >> 14;
    dst[r] = (bf16)src[(o * 128 + i) * Kw + k];
}

// ---------------- prep: centers fp32 -> bf16, plus ||c||^2 ----------------
__global__ void k_prep_c(const float* __restrict__ c, bf16* __restrict__ cb,
                         float* __restrict__ cc) {
    int k = blockIdx.x;
    int tid = threadIdx.x;
    const float* row = c + k * 7552;
    bf16* orow = cb + k * 7552;
    float s = 0.f;
    for (int d = tid; d < 7552; d += 256) {
        bf16 b = (bf16)row[d];
        orow[d] = b;
        float v = (float)b;
        s += v * v;
    }
    __shared__ float red[256];
    red[tid] = s;
    __syncthreads();
    for (int st = 128; st > 0; st >>= 1) {
        if (tid < st) red[tid] += red[tid + st];
        __syncthreads();
    }
    if (tid == 0) cc[k] = red[0];
}

// ---------------- conv layer: implicit GEMM, bf16 MFMA ----------------
// out[n][o][l] = act( sum_{i,k} w[o][i][k] * in[n][i][2*l+k] + bias[o] )
// m=o (128), n=l (LT tile), K = 32-channel chunk at fixed tap k.
// A: wT[k][o][i] 16B global loads, register double-buffered (prefetch j+1).
// B: LDS rows of 64 ch per position, slot=(i>>3)^((p>>1)&7):
//    b128 reads conflict-free; channel-fast staging writes 2-way (free).
// 4 blocks/CU (launch_bounds(256,4)): co-resident waves hide A/staging latency.
template <int KW, int LIN_S, int LIN_V, int LOUT_S, int LOUT_V, int LT, bool ACT, bool IN_F32>
__global__ __launch_bounds__(256, 4) void k_conv(
    const void* __restrict__ in_, const bf16* __restrict__ wT,
    const float* __restrict__ bias, bf16* __restrict__ out) {
    constexpr int P = (LT - 1) * 2 + KW;   // input positions needed by this tile
    constexpr int PP = (P + 7) & ~7;       // padded to vec width
    constexpr int VW = IN_F32 ? 4 : 8;     // elems per 16B staging load
    constexpr int NV = PP / VW;            // vec chunks per channel row
    constexpr int TOT = 64 * NV;           // staging units per phase
    constexpr int NIT = (TOT + 255) / 256;
    constexpr bool TG = (TOT & 255) != 0;
    constexpr int WLS = LT / 2;            // l-span per wave
    constexpr int NLT = WLS / 16;          // 16-wide l-tiles per wave
    constexpr int SE = LT + 8;             // epilogue LDS row stride
    constexpr int SM = (PP * 64 > 128 * SE) ? PP * 64 : 128 * SE;
    __shared__ __align__(16) bf16 smem[SM];

    const int n = blockIdx.y;
    const int l0 = blockIdx.x * LT;
    const int p0 = l0 * 2;
    const int tid = threadIdx.x;
    const int wid = tid >> 6;
    const int lane = tid & 63;
    const int quad = lane >> 4;
    const int l15 = lane & 15;
    const int wave_o = (wid >> 1) * 64;   // 2x2 wave grid: 64o x WLS l per wave
    const int wave_l = (wid & 1) * WLS;

    const float* __restrict__ inF = (const float*)in_;
    const bf16* __restrict__ inB = (const bf16*)in_;

    f32x4 acc[4][NLT];
#pragma unroll
    for (int a = 0; a < 4; ++a)
#pragma unroll
        for (int b = 0; b < NLT; ++b) acc[a][b] = (f32x4){0.f, 0.f, 0.f, 0.f};

    bf16x8 afr[2][4];
    const int aoff = (wave_o + l15) * CCH + quad * 8;  // lane part of A address

#pragma unroll 1
    for (int phase = 0; phase < 2; ++phase) {
        const int cbase = phase * 64;
        __syncthreads();  // protect smem against overwrite (phase 1)

        // prefetch A for j=0 of this phase (global; overlaps staging)
        {
            const bf16* wp = wT + aoff + cbase;
#pragma unroll
            for (int ot = 0; ot < 4; ++ot) afr[0][ot] = *(const bf16x8*)(wp + ot * 16 * CCH);
        }

        // stage channels [cbase, cbase+64) x positions [p0, p0+PP) -> swizzled LDS
        // lane = channel (i), v wave-uniform: LDS writes 2-way bank aliased (free)
#pragma unroll 4
        for (int it = 0; it < NIT; ++it) {
            int idx = tid + it * 256;
            if (!TG || idx < TOT) {
                int i = idx & 63;
                int v = idx >> 6;
                int gp0 = p0 + v * VW;
                float vals[VW];
                const char* rowb = IN_F32
                    ? (const char*)(inF + (size_t)(n * CCH + cbase + i) * LIN_S)
                    : (const char*)(inB + (size_t)(n * CCH + cbase + i) * LIN_S);
                if (gp0 + VW <= LIN_V) {
                    if (IN_F32) {
                        f32x4 t = *(const f32x4*)((const float*)rowb + gp0);
#pragma unroll
                        for (int e = 0; e < VW; ++e) vals[e] = t[e & 3];
                    } else {
                        bf16x8 t = *(const bf16x8*)((const bf16*)rowb + gp0);
#pragma unroll
                        for (int e = 0; e < VW; ++e) vals[e] = (float)t[e & 7];
                    }
                } else {
#pragma unroll
                    for (int e = 0; e < VW; ++e) {
                        int gp = gp0 + e;
                        vals[e] = 0.f;
                        if (gp < LIN_V)
                            vals[e] = IN_F32 ? ((const float*)rowb)[gp]
                                             : (float)((const bf16*)rowb)[gp];
                    }
                }
#pragma unroll
                for (int e = 0; e < VW; ++e) {
                    int p = v * VW + e;
                    int slot = (i >> 3) ^ ((p >> 1) & 7);
                    smem[p * 64 + slot * 8 + (i & 7)] = (bf16)vals[e];
                }
            }
        }
        __syncthreads();

        // K-loop: j = (k, ic) flattened; A double-buffered one iter ahead
#pragma unroll 2
        for (int j = 0; j < 2 * KW; ++j) {
            if (j + 1 < 2 * KW) {
                int k1 = (j + 1) >> 1;
                const bf16* wp = wT + (size_t)k1 * CCH * CCH + aoff + cbase + ((j + 1) & 1) * 32;
#pragma unroll
                for (int ot = 0; ot < 4; ++ot)
                    afr[(j + 1) & 1][ot] = *(const bf16x8*)(wp + ot * 16 * CCH);
            }
            const int k = j >> 1;
            const int icq = (j & 1) * 4 + quad;  // (ic*32 + quad*8) >> 3
#pragma unroll
            for (int lt = 0; lt < NLT; ++lt) {
                int p = (wave_l + lt * 16 + l15) * 2 + k;
                int slot = icq ^ ((p >> 1) & 7);
                bf16x8 bfr = *(const bf16x8*)(smem + p * 64 + slot * 8);
#pragma unroll
                for (int ot = 0; ot < 4; ++ot)
                    acc[ot][lt] = __builtin_amdgcn_mfma_f32_16x16x32_bf16(
                        afr[j & 1][ot], bfr, acc[ot][lt], 0, 0, 0);
            }
        }
    }

    // ---- epilogue: bias+act, LDS transpose, wide contiguous stores ----
    __syncthreads();  // all B-reads of smem done
#pragma unroll
    for (int ot = 0; ot < 4; ++ot) {
        const int o0 = wave_o + ot * 16 + quad * 4;
#pragma unroll
        for (int lt = 0; lt < NLT; ++lt) {
            const int l = wave_l + lt * 16 + l15;
#pragma unroll
            for (int r = 0; r < 4; ++r) {
                float v = acc[ot][lt][r] + bias[o0 + r];
                if (ACT) v = (v > 0.f) ? v : 0.1f * v;
                smem[(o0 + r) * SE + l] = (bf16)v;
            }
        }
    }
    __syncthreads();
    constexpr int GPR = LT / 8;  // 16B groups per o-row (pow2)
#pragma unroll
    for (int it = 0; it < 128 * GPR / 256; ++it) {
        int unit = tid + it * 256;
        int o = unit / GPR;
        int g = unit & (GPR - 1);
        bf16x8 vv = *(const bf16x8*)(smem + o * SE + g * 8);
        *(bf16x8*)(out + (size_t)(n * CCH + o) * LOUT_S + l0 + g * 8) = vv;
    }
}

// ---------------- distances + Student-t assignment ----------------
// z rows padded: stride 64, valid 59; dense d = o*59 + l matches centers.
__global__ __launch_bounds__(512) void k_dist(
    const bf16* __restrict__ z, const bf16* __restrict__ cb,
    const float* __restrict__ cc, float* __restrict__ out) {
    __shared__ float zsh[7552];
    __shared__ float red[512];
    __shared__ float qsh[64];
    const int n = blockIdx.x;
    const int tid = threadIdx.x;
    const bf16* zr = z + (size_t)n * CCH * 64;
    float zz = 0.f;
    for (int dd = tid; dd < 7552; dd += 512) {
        int o = dd / 59;
        int l = dd - o * 59;
        float v = (float)zr[o * 64 + l];
        zsh[dd] = v;
        zz += v * v;
    }
    red[tid] = zz;
    __syncthreads();
    for (int st = 256; st > 0; st >>= 1) {
        if (tid < st) red[tid] += red[tid + st];
        __syncthreads();
    }
    const float zz_val = red[0];
    __syncthreads();  // all threads have read red[0] before red is reused

    const int k = tid >> 3;    // center 0..63
    const int part = tid & 7;  // eighth of D (944 elems)
    const bf16* cr = cb + k * 7552 + part * 944;
    const float* zp = zsh + part * 944;
    float s = 0.f;
    for (int d = 0; d < 944; d += 8) {
        bf16x8 cv = *(const bf16x8*)(cr + d);
        f32x4 z0 = *(const f32x4*)(zp + d);
        f32x4 z1 = *(const f32x4*)(zp + d + 4);
#pragma unroll
        for (int j = 0; j < 4; ++j) s += z0[j] * (float)cv[j];
#pragma unroll
        for (int j = 0; j < 4; ++j) s += z1[j] * (float)cv[4 + j];
    }
    red[tid] = s;
    __syncthreads();
    if (tid < 64) {
        float dot = 0.f;
#pragma unroll
        for (int e = 0; e < 8; ++e) dot += red[tid * 8 + e];
        float d2 = zz_val + cc[tid] - 2.f * dot;
        qsh[tid] = 1.f / (1.f + d2);  // ALPHA=1, exponent (ALPHA+1)/2 == 1
    }
    __syncthreads();
    if (tid < 64) {
        float q = qsh[tid];
        float tot = q;
        for (int o = 32; o > 0; o >>= 1) tot += __shfl_down(tot, o);
        tot = __shfl(tot, 0);
        out[n * 64 + tid] = q / tot;
    }
}

// ---------------- launcher ----------------
extern "C" void kernel_launch(void* const* d_in, const int* in_sizes, int n_in,
                              void* d_out, int out_size, void* d_ws, size_t ws_size,
                              hipStream_t stream) {
    (void)in_sizes; (void)n_in; (void)out_size; (void)ws_size;
    const float* x   = (const float*)d_in[0];
    const float* w1  = (const float*)d_in[1];
    const float* b1  = (const float*)d_in[2];
    const float* w2  = (const float*)d_in[3];
    const float* b2  = (const float*)d_in[4];
    const float* w3  = (const float*)d_in[5];
    const float* b3  = (const float*)d_in[6];
    const float* w4  = (const float*)d_in[7];
    const float* b4  = (const float*)d_in[8];
    const float* cen = (const float*)d_in[9];
    float* out = (float*)d_out;

    char* ws = (char*)d_ws;
    size_t off = 0;
    auto alloc = [&](size_t bytes) -> void* {
        void* p = ws + off;
        off += (bytes + 255) & ~(size_t)255;
        return p;
    };
    bf16* wT1 = (bf16*)alloc((size_t)15 * 16384 * sizeof(bf16));
    bf16* wT2 = (bf16*)alloc((size_t)12 * 16384 * sizeof(bf16));
    bf16* wT3 = (bf16*)alloc((size_t)7 * 16384 * sizeof(bf16));
    bf16* wT4 = (bf16*)alloc((size_t)4 * 16384 * sizeof(bf16));
    bf16* cb  = (bf16*)alloc((size_t)64 * 7552 * sizeof(bf16));
    float* cc = (float*)alloc(64 * sizeof(float));
    // padded intermediates: strides 512/256/128/64 (16B-aligned rows)
    bf16* h1  = (bf16*)alloc((size_t)256 * 128 * 512 * sizeof(bf16));
    bf16* h2  = (bf16*)alloc((size_t)256 * 128 * 256 * sizeof(bf16));
    bf16* h3  = h1;  // reuse: h1 dead after conv2 (needs 128-stride)
    bf16* h4  = h2;  // reuse: h2 dead after conv3 (needs 64-stride)

    k_prep_wall<<<(38 * 16384 + 255) / 256, 256, 0, stream>>>(w1, w2, w3, w4, wT1, wT2, wT3, wT4);
    k_prep_c<<<64, 256, 0, stream>>>(cen, cb, cc);

    // conv1: 1024 -> 505(512) K=15, LeakyReLU, fp32 input; 1024 blocks = 4/CU, 1 round
    k_conv<15, 1024, 1024, 512, 505, 128, true, true>
        <<<dim3(4, 256), 256, 0, stream>>>(x, wT1, b1, h1);
    // conv2: 505(512) -> 247(256) K=12, LeakyReLU; LT=64 -> 1024 blocks
    k_conv<12, 512, 505, 256, 247, 64, true, false>
        <<<dim3(4, 256), 256, 0, stream>>>(h1, wT2, b2, h2);
    // conv3: 247(256) -> 121(128) K=7, LeakyReLU
    k_conv<7, 256, 247, 128, 121, 64, true, false>
        <<<dim3(2, 256), 256, 0, stream>>>(h2, wT3, b3, h3);
    // conv4: 121(128) -> 59(64) K=4, no activation
    k_conv<4, 128, 121, 64, 59, 32, false, false>
        <<<dim3(2, 256), 256, 0, stream>>>(h3, wT4, b4, h4);

    k_dist<<<256, 512, 0, stream>>>(h4, cb, cc, out);
}